// Round 11
// baseline (275.305 us; speedup 1.0000x reference)
//
#include <hip/hip_runtime.h>
#include <math.h>

#define NROW 8192
#define DDIM 256
#define BM 128
#define BN 64           // column-half blocks: wave tile 64x32 -> 32 acc regs
#define BK 128
#define NT_SYM 2080     // 64*65/2 lower-triangular 128x128 logical tiles
#define NT_FULL 4096
#define NT_TOTAL (2 * NT_SYM + NT_FULL)   // 8256 logical tiles
#define GRID (2 * NT_TOTAL)               // 2 column-halves each = 16512

typedef __attribute__((ext_vector_type(16))) float f32x16;
typedef __attribute__((ext_vector_type(4)))  int   i32x4;
typedef __attribute__((ext_vector_type(8)))  int   i32x8;
typedef __attribute__((address_space(3))) unsigned int lds_u32;
typedef const __attribute__((address_space(1))) unsigned int glb_u32;

// DPP row_ror butterfly add: after ror 1,2,4,8 every lane of each 16-lane row
// holds the row sum. VALU pipe only — no DS traffic.
template <int CTRL>
static __device__ inline float dpp_ror_add(float v) {
    int s = __float_as_int(v);
    int r = __builtin_amdgcn_update_dpp(0, s, CTRL, 0xF, 0xF, true);
    return v + __int_as_float(r);
}
static __device__ inline float row16_sum(float v) {
    v = dpp_ror_add<0x121>(v);
    v = dpp_ror_add<0x122>(v);
    v = dpp_ror_add<0x124>(v);
    v = dpp_ror_add<0x128>(v);
    return v;
}

// Pack 4 floats -> 4 fp8 e4m3 bytes (HW cvt, OCP on gfx950 — self-consistent
// with the fp8 MFMA's decode).
static __device__ inline unsigned int pack_fp8x4(float a, float b, float c, float d) {
    int p = __builtin_amdgcn_cvt_pk_fp8_f32(a, b, 0, false);
    p = __builtin_amdgcn_cvt_pk_fp8_f32(c, d, p, true);
    return (unsigned int)p;
}

// One wave per row: L2-normalize H1/H2 rows, scale by sqrt(2*log2(e)) so the
// fp8 Gram entries come out as 2*log2(e)*s -> exp(2s) == exp2(acc).
// diag[row] = 2*dot(z1n,z2n) fp32 (exact). Zero-inits rowsums, out, ticket.
__global__ __launch_bounds__(256) void normalize_kernel(
        const float* __restrict__ h1, const float* __restrict__ h2,
        unsigned char* __restrict__ z1b, unsigned char* __restrict__ z2b,
        float* __restrict__ diag,
        float* __restrict__ rs1, float* __restrict__ rs2,
        float* __restrict__ rbr, float* __restrict__ rbc,
        float* __restrict__ out, unsigned int* __restrict__ cnt) {
    int wave = threadIdx.x >> 6;
    int lane = threadIdx.x & 63;
    int row  = blockIdx.x * 4 + wave;
    if (blockIdx.x == 0 && threadIdx.x == 0) { out[0] = 0.f; cnt[0] = 0u; }
    const float4* p1 = (const float4*)(h1 + (size_t)row * DDIM);
    const float4* p2 = (const float4*)(h2 + (size_t)row * DDIM);
    float4 a = p1[lane];
    float4 b = p2[lane];
    float s1 = a.x*a.x + a.y*a.y + a.z*a.z + a.w*a.w;
    float s2 = b.x*b.x + b.y*b.y + b.z*b.z + b.w*b.w;
    #pragma unroll
    for (int m = 1; m < 64; m <<= 1) { s1 += __shfl_xor(s1, m); s2 += __shfl_xor(s2, m); }
    float r1 = 1.0f / fmaxf(sqrtf(s1), 1e-12f);
    float r2 = 1.0f / fmaxf(sqrtf(s2), 1e-12f);
    float n1x = a.x*r1, n1y = a.y*r1, n1z = a.z*r1, n1w = a.w*r1;
    float n2x = b.x*r2, n2y = b.y*r2, n2z = b.z*r2, n2w = b.w*r2;
    float dt = n1x*n2x + n1y*n2y + n1z*n2z + n1w*n2w;
    #pragma unroll
    for (int m = 1; m < 64; m <<= 1) dt += __shfl_xor(dt, m);
    if (lane == 0) {
        diag[row] = 2.0f * dt;
        rs1[row] = 0.f; rs2[row] = 0.f; rbr[row] = 0.f; rbc[row] = 0.f;
    }
    const float SC = 1.69864364f;   // sqrt(2 * log2(e))
    ((unsigned int*)(z1b + (size_t)row * DDIM))[lane] =
        pack_fp8x4(n1x*SC, n1y*SC, n1z*SC, n1w*SC);
    ((unsigned int*)(z2b + (size_t)row * DDIM))[lane] =
        pack_fp8x4(n2x*SC, n2y*SC, n2z*SC, n2w*SC);
}

// R14 = R10 compute core EXACTLY (89 us local optimum; R13's direct-gather
// probe cost 2x and vindicated the LDS path) + fence-free fused finalize.
// R11's fusion failed because of 16512 per-block __threadfence() L2
// writebacks. Fence-free: __syncthreads() after the epilogue atomics drains
// each wave's VMEM (atomics complete AT L2, device-scope). Then ONE ticket
// atomicAdd; the block seeing old==GRID-1 knows all other blocks' rowsum
// atomics are durable -> it alone runs the 8192-row finalize inline
// (agent-scope atomic loads bypass L1). No spin, no fence anywhere.
__global__ __launch_bounds__(256, 6) void expsum_kernel(
        const unsigned char* __restrict__ z1, const unsigned char* __restrict__ z2,
        float* __restrict__ rs1, float* __restrict__ rs2,
        float* __restrict__ rbr, float* __restrict__ rbc,
        const float* __restrict__ diag, float* __restrict__ out,
        unsigned int* __restrict__ cnt) {
    int t  = blockIdx.x >> 1;
    int ch = blockIdx.x & 1;           // which 64-col half of the 128x128 tile
    int kind, tt;
    if (t < NT_SYM)            { kind = 0; tt = t; }
    else if (t < 2 * NT_SYM)   { kind = 1; tt = t - NT_SYM; }
    else                       { kind = 2; tt = t - 2 * NT_SYM; }

    int by, bx;
    const unsigned char *Ap, *Bp;
    float *rowsum, *colsum;
    if (kind == 2) {
        by = tt >> 6; bx = tt & 63;
        Ap = z1; Bp = z2; rowsum = rbr; colsum = rbc;
    } else {
        by = (int)((sqrtf(8.0f * (float)tt + 1.0f) - 1.0f) * 0.5f);
        while ((by + 1) * (by + 2) / 2 <= tt) ++by;
        while (by * (by + 1) / 2 > tt) --by;
        bx = tt - by * (by + 1) / 2;          // bx <= by
        const unsigned char* z = (kind == 0) ? z1 : z2;
        Ap = z; Bp = z;
        rowsum = (kind == 0) ? rs1 : rs2;
        colsum = (bx == by) ? nullptr : rowsum;
    }

    const int rt = by * BM;
    const int ct = bx * BM + ch * BN;    // global col base of this half

    __shared__ __align__(16) unsigned char lA[BM * BK];  // 16 KB
    __shared__ float lds_rp[2][2][BM];                   // [wc][colhalf][row] 2 KB
    __shared__ float lds_cp[2][2][BN];                   // [wr][kh][col]      1 KB
    __shared__ unsigned int s_tk;
    __shared__ float fin4[4];

    const int tid  = threadIdx.x;
    const int lane = tid & 63;
    const int wid  = tid >> 6;
    const int wr   = wid & 1;            // 64-row half
    const int wc   = wid >> 1;           // 32-col quarter (of the 64-col tile)
    const int l31  = lane & 31;
    const int kh   = lane >> 5;          // k-half of the 64-wide k-step

    // DMA lane mapping: 8 lanes per 128-B row, 8 rows per wave-instruction.
    const int srow = lane >> 3;          // row within 8-row group
    const int sgt  = lane & 7;           // physical 16B granule (= DMA slot)

    const int sw16 = (l31 & 7);          // row-swizzle key for reads

    const int aoff0 = (wr * 64 + l31) * BK;          // rows 0..31 of wave tile
    const int aoff1 = aoff0 + 32 * BK;               // rows 32..63

    // A DMA pointers precomputed once; kt=1 reuses with +128 imm offset.
    const unsigned char* gA[4];
    lds_u32* ldA[4];
    #pragma unroll
    for (int p = 0; p < 4; ++p) {
        int r0 = (p * 4 + wid) * 8;
        int r  = r0 + srow;
        int gg = sgt ^ (r & 7);
        gA[p]  = Ap + (size_t)(rt + r) * DDIM + gg * 16;
        ldA[p] = (lds_u32*)(lA + r0 * BK);
    }
    // B direct-load base: lane holds row (ct + wc*32 + l31), k-bytes
    // kh*32 + imm. All 8 fragment loads are this base + compile-time imm.
    const unsigned char* gBbase =
        Bp + (size_t)(ct + wc * 32 + l31) * DDIM + kh * 32;

    f32x16 acc0, acc1;
    #pragma unroll
    for (int r = 0; r < 16; ++r) { acc0[r] = 0.f; acc1[r] = 0.f; }

    #pragma unroll
    for (int kt = 0; kt < 2; ++kt) {
        // Stage A (128x128B: 16 DMAs, 4/wave); B goes straight to VGPRs.
        if (kt == 0) {
            #pragma unroll
            for (int p = 0; p < 4; ++p)
                __builtin_amdgcn_global_load_lds((glb_u32*)gA[p], ldA[p], 16, 0, 0);
        } else {
            #pragma unroll
            for (int p = 0; p < 4; ++p)
                __builtin_amdgcn_global_load_lds((glb_u32*)gA[p], ldA[p], 16, 128, 0);
        }
        // Issue this kt's 4 B fragment loads (2 ks x 2 halves, 16 regs).
        i32x8 bv0, bv1;
        *((i32x4*)&bv0)     = *(const i32x4*)(gBbase + kt * 128);
        *((i32x4*)&bv0 + 1) = *(const i32x4*)(gBbase + kt * 128 + 16);
        *((i32x4*)&bv1)     = *(const i32x4*)(gBbase + kt * 128 + 64);
        *((i32x4*)&bv1 + 1) = *(const i32x4*)(gBbase + kt * 128 + 80);
        __syncthreads();                 // drains vmcnt: A in LDS, B in regs
        #pragma unroll
        for (int ks = 0; ks < 2; ++ks) {            // 2 x K=64 per k-tile
            const int g0   = ks * 4 + kh * 2;       // logical even granule
            const int off0 = (g0 ^ sw16) * 16;
            const int off1 = off0 ^ 16;             // odd partner granule
            i32x8 a0, a1;
            *((i32x4*)&a0)     = *(const i32x4*)(lA + aoff0 + off0);
            *((i32x4*)&a0 + 1) = *(const i32x4*)(lA + aoff0 + off1);
            *((i32x4*)&a1)     = *(const i32x4*)(lA + aoff1 + off0);
            *((i32x4*)&a1 + 1) = *(const i32x4*)(lA + aoff1 + off1);
            const i32x8 bv = (ks == 0) ? bv0 : bv1;
            acc0 = __builtin_amdgcn_mfma_scale_f32_32x32x64_f8f6f4(
                a0, bv, acc0, 0, 0, 0, 0x7F7F7F7F, 0, 0x7F7F7F7F);
            acc1 = __builtin_amdgcn_mfma_scale_f32_32x32x64_f8f6f4(
                a1, bv, acc1, 0, 0, 0, 0x7F7F7F7F, 0, 0x7F7F7F7F);
        }
        __syncthreads();
    }

    // C/D layout (32x32): col = lane&31, row = (reg&3) + 8*(reg>>2) + 4*kh.
    // acc = 2*log2e*s -> raw v_exp_f32 (inputs bounded ~|2.9|).
    // No shuffles: after row16_sum each 16-lane group's lane 0 (lanes
    // 0/16/32/48) holds a 16-col x kh-half partial -> write to its own
    // [wc][colhalf] scratch plane. Col partials: every lane writes its
    // [wr][kh] plane. Final pass sums 4 planes -> ONE atomic per row/col.
    float cp0 = 0.f, cp1 = 0.f;
    #pragma unroll
    for (int r = 0; r < 16; ++r) {
        float e0 = __builtin_amdgcn_exp2f(acc0[r]);
        float e1 = __builtin_amdgcn_exp2f(acc1[r]);
        cp0 += e0;
        cp1 += e1;
        float v0 = row16_sum(e0);
        float v1 = row16_sum(e1);
        if ((lane & 15) == 0) {          // lanes 0,16,32,48
            int rloc = wr * 64 + 4 * kh + (r & 3) + 8 * (r >> 2);
            int colhalf = l31 >> 4;      // 0 for lanes 0/32, 1 for 16/48
            lds_rp[wc][colhalf][rloc]      = v0;
            lds_rp[wc][colhalf][rloc + 32] = v1;
        }
    }
    lds_cp[wr][kh][wc * 32 + l31] = cp0 + cp1;
    __syncthreads();
    if (tid < BM) {
        float s = lds_rp[0][0][tid] + lds_rp[0][1][tid]
                + lds_rp[1][0][tid] + lds_rp[1][1][tid];
        atomicAdd(&rowsum[rt + tid], s);
    } else if (colsum && tid < BM + BN) {
        int c = tid - BM;
        float s = lds_cp[0][0][c] + lds_cp[0][1][c]
                + lds_cp[1][0][c] + lds_cp[1][1][c];
        atomicAdd(&colsum[ct + c], s);
    }

    // ---- fence-free fused finalize ----
    // __syncthreads() waits each wave's outstanding VMEM (incl. the atomics
    // above, which complete AT L2, device-scope). The single block whose
    // ticket == GRID-1 therefore knows every block's sums are durable.
    __syncthreads();
    if (tid == 0) s_tk = atomicAdd(cnt, 1u);
    __syncthreads();
    if (s_tk == (unsigned int)(GRID - 1)) {
        const float E2 = 7.38905609893065f;   // exp(1/tau), tau=0.5
        float v = 0.f;
        for (int i = tid; i < NROW; i += 256) {
            float a1 = __hip_atomic_load(&rs1[i], __ATOMIC_RELAXED, __HIP_MEMORY_SCOPE_AGENT);
            float a2 = __hip_atomic_load(&rs2[i], __ATOMIC_RELAXED, __HIP_MEMORY_SCOPE_AGENT);
            float b1 = __hip_atomic_load(&rbr[i], __ATOMIC_RELAXED, __HIP_MEMORY_SCOPE_AGENT);
            float b2 = __hip_atomic_load(&rbc[i], __ATOMIC_RELAXED, __HIP_MEMORY_SCOPE_AGENT);
            float den1 = a1 + b1 - E2;
            float den2 = a2 + b2 - E2;
            v += 0.5f * (logf(den1) + logf(den2)) - diag[i];
        }
        #pragma unroll
        for (int m = 1; m < 64; m <<= 1) v += __shfl_xor(v, m);
        if ((tid & 63) == 0) fin4[tid >> 6] = v;
        __syncthreads();
        if (tid == 0)
            out[0] = (fin4[0] + fin4[1] + fin4[2] + fin4[3]) * (1.0f / (float)NROW);
    }
}

extern "C" void kernel_launch(void* const* d_in, const int* in_sizes, int n_in,
                              void* d_out, int out_size, void* d_ws, size_t ws_size,
                              hipStream_t stream) {
    const float* h1 = (const float*)d_in[0];
    const float* h2 = (const float*)d_in[1];
    float* out = (float*)d_out;

    char* ws = (char*)d_ws;
    unsigned char* z1b = (unsigned char*)ws;                             // 2 MB
    unsigned char* z2b = (unsigned char*)(ws + (size_t)NROW * DDIM);     // 2 MB
    float* sums = (float*)(ws + (size_t)2 * NROW * DDIM);
    float* rs1  = sums;
    float* rs2  = sums + NROW;
    float* rbr  = sums + 2 * NROW;
    float* rbc  = sums + 3 * NROW;
    float* diag = sums + 4 * NROW;
    unsigned int* cnt = (unsigned int*)(sums + 5 * NROW);

    normalize_kernel<<<NROW / 4, 256, 0, stream>>>(h1, h2, z1b, z2b, diag,
                                                   rs1, rs2, rbr, rbc, out, cnt);

    expsum_kernel<<<GRID, 256, 0, stream>>>(z1b, z2b, rs1, rs2, rbr, rbc,
                                            diag, out, cnt);
}

// Round 13
// 145.872 us; speedup vs baseline: 1.8873x; 1.8873x over previous
//
#include <hip/hip_runtime.h>
#include <math.h>

#define NROW 8192
#define DDIM 256
#define BM 128
#define BN 128          // full tile per block; two 64-col halves sequentially
#define NT_SYM 2080     // 64*65/2 lower-triangular 128x128 tiles
#define NT_FULL 4096
#define NT_TOTAL (2 * NT_SYM + NT_FULL)   // 8256 tiles = grid

typedef __attribute__((ext_vector_type(16))) float f32x16;
typedef __attribute__((ext_vector_type(4)))  int   i32x4;
typedef __attribute__((ext_vector_type(8)))  int   i32x8;
typedef __attribute__((address_space(3))) unsigned int lds_u32;
typedef const __attribute__((address_space(1))) unsigned int glb_u32;

// DPP row_ror butterfly add: after ror 1,2,4,8 every lane of each 16-lane row
// holds the row sum. VALU pipe only — no DS traffic.
template <int CTRL>
static __device__ inline float dpp_ror_add(float v) {
    int s = __float_as_int(v);
    int r = __builtin_amdgcn_update_dpp(0, s, CTRL, 0xF, 0xF, true);
    return v + __int_as_float(r);
}
static __device__ inline float row16_sum(float v) {
    v = dpp_ror_add<0x121>(v);
    v = dpp_ror_add<0x122>(v);
    v = dpp_ror_add<0x124>(v);
    v = dpp_ror_add<0x128>(v);
    return v;
}

// Pack 4 floats -> 4 fp8 e4m3 bytes (HW cvt, OCP on gfx950 — self-consistent
// with the fp8 MFMA's decode).
static __device__ inline unsigned int pack_fp8x4(float a, float b, float c, float d) {
    int p = __builtin_amdgcn_cvt_pk_fp8_f32(a, b, 0, false);
    p = __builtin_amdgcn_cvt_pk_fp8_f32(c, d, p, true);
    return (unsigned int)p;
}

// One wave per row: L2-normalize H1/H2 rows, scale by sqrt(2*log2(e)) so the
// fp8 Gram entries come out as 2*log2(e)*s -> exp(2s) == exp2(acc).
// diag[row] = 2*dot(z1n,z2n) fp32 (exact). Zero-inits rowsums and out.
__global__ __launch_bounds__(256) void normalize_kernel(
        const float* __restrict__ h1, const float* __restrict__ h2,
        unsigned char* __restrict__ z1b, unsigned char* __restrict__ z2b,
        float* __restrict__ diag,
        float* __restrict__ rs1, float* __restrict__ rs2,
        float* __restrict__ rbr, float* __restrict__ rbc,
        float* __restrict__ out) {
    int wave = threadIdx.x >> 6;
    int lane = threadIdx.x & 63;
    int row  = blockIdx.x * 4 + wave;
    if (blockIdx.x == 0 && threadIdx.x == 0) out[0] = 0.f;
    const float4* p1 = (const float4*)(h1 + (size_t)row * DDIM);
    const float4* p2 = (const float4*)(h2 + (size_t)row * DDIM);
    float4 a = p1[lane];
    float4 b = p2[lane];
    float s1 = a.x*a.x + a.y*a.y + a.z*a.z + a.w*a.w;
    float s2 = b.x*b.x + b.y*b.y + b.z*b.z + b.w*b.w;
    #pragma unroll
    for (int m = 1; m < 64; m <<= 1) { s1 += __shfl_xor(s1, m); s2 += __shfl_xor(s2, m); }
    float r1 = 1.0f / fmaxf(sqrtf(s1), 1e-12f);
    float r2 = 1.0f / fmaxf(sqrtf(s2), 1e-12f);
    float n1x = a.x*r1, n1y = a.y*r1, n1z = a.z*r1, n1w = a.w*r1;
    float n2x = b.x*r2, n2y = b.y*r2, n2z = b.z*r2, n2w = b.w*r2;
    float dt = n1x*n2x + n1y*n2y + n1z*n2z + n1w*n2w;
    #pragma unroll
    for (int m = 1; m < 64; m <<= 1) dt += __shfl_xor(dt, m);
    if (lane == 0) {
        diag[row] = 2.0f * dt;
        rs1[row] = 0.f; rs2[row] = 0.f; rbr[row] = 0.f; rbc[row] = 0.f;
    }
    const float SC = 1.69864364f;   // sqrt(2 * log2(e))
    ((unsigned int*)(z1b + (size_t)row * DDIM))[lane] =
        pack_fp8x4(n1x*SC, n1y*SC, n1z*SC, n1w*SC);
    ((unsigned int*)(z2b + (size_t)row * DDIM))[lane] =
        pack_fp8x4(n2x*SC, n2y*SC, n2z*SC, n2w*SC);
}

// R15: full 128x128 tile per block (grid 16512 -> 8256), A panel staged ONCE
// as 128x256B (32 KB) with a 4-bit granule swizzle g^(r&15); the two 64-col
// halves run sequentially (#pragma unroll 1 keeps acc at 32 AGPR and stops
// cross-half CSE), no barrier between them -> their chains overlap via ILP.
// Per unit this halves launch/decode overhead, A-stage DMAs and barriers
// (2 per block total). Evidence basis: dur x occupancy ~ const across R4-R12
// (throughput ~ units-in-flight); 4 blocks/CU x 2-unit ILP ~ 8 units vs 5.2.
// Fusion attempts abandoned (R11: acquire-spin thrash; R14: 16512
// same-address ticket atomics serialize ~120us).
//
// Scratch: zero-init planes once, both halves owner-lane "+=" (race-free),
// one final combine -> 256 atomics per block.
__global__ __launch_bounds__(256, 4) void expsum_kernel(
        const unsigned char* __restrict__ z1, const unsigned char* __restrict__ z2,
        float* __restrict__ rs1, float* __restrict__ rs2,
        float* __restrict__ rbr, float* __restrict__ rbc) {
    int t = blockIdx.x;
    int kind, tt;
    if (t < NT_SYM)            { kind = 0; tt = t; }
    else if (t < 2 * NT_SYM)   { kind = 1; tt = t - NT_SYM; }
    else                       { kind = 2; tt = t - 2 * NT_SYM; }

    int by, bx;
    const unsigned char *Ap, *Bp;
    float *rowsum, *colsum;
    if (kind == 2) {
        by = tt >> 6; bx = tt & 63;
        Ap = z1; Bp = z2; rowsum = rbr; colsum = rbc;
    } else {
        by = (int)((sqrtf(8.0f * (float)tt + 1.0f) - 1.0f) * 0.5f);
        while ((by + 1) * (by + 2) / 2 <= tt) ++by;
        while (by * (by + 1) / 2 > tt) --by;
        bx = tt - by * (by + 1) / 2;          // bx <= by
        const unsigned char* z = (kind == 0) ? z1 : z2;
        Ap = z; Bp = z;
        rowsum = (kind == 0) ? rs1 : rs2;
        colsum = (bx == by) ? nullptr : rowsum;
    }

    const int rt = by * BM;
    const int ct = bx * BN;

    __shared__ __align__(16) unsigned char lA[BM * DDIM];  // 32 KB full-K A
    __shared__ float lds_rp[2][2][BM];                     // [wc][sub16][row] 2 KB
    __shared__ float lds_cp[2][2][BN];                     // [wr][kh][col]    2 KB

    const int tid  = threadIdx.x;
    const int lane = tid & 63;
    const int wid  = tid >> 6;
    const int wr   = wid & 1;            // 64-row half
    const int wc   = wid >> 1;           // 32-col quarter (of a 64-col half)
    const int l31  = lane & 31;
    const int kh   = lane >> 5;          // k-half of the 64-wide k-step

    // DMA lane mapping: 16 lanes per 256-B row, 4 rows per wave-instruction.
    const int srow = lane >> 4;          // row within 4-row group
    const int sgt  = lane & 15;          // physical 16B granule (= DMA slot)

    const int key  = lane & 15;          // read-side swizzle key (= row&15)

    const int aoff0 = (wr * 64 + l31) * DDIM;        // rows 0..31 of wave tile
    const int aoff1 = aoff0 + 32 * DDIM;             // rows 32..63

    // Zero the reduction scratch (1024 floats / 256 threads = 4 each).
    {
        ((float*)lds_rp)[tid]       = 0.f;
        ((float*)lds_rp)[tid + 256] = 0.f;
        ((float*)lds_cp)[tid]       = 0.f;
        ((float*)lds_cp)[tid + 256] = 0.f;
    }

    // Stage full 128x256B A: 32 wave-DMAs, 8 per wave, 16 B/lane, linear
    // dest, swizzled source granule gg = sgt ^ (r&15).
    #pragma unroll
    for (int p = 0; p < 8; ++p) {
        int r0 = (p * 4 + wid) * 4;
        int r  = r0 + srow;
        int gg = sgt ^ (r & 15);
        const unsigned char* ga = Ap + (size_t)(rt + r) * DDIM + gg * 16;
        __builtin_amdgcn_global_load_lds((glb_u32*)ga, (lds_u32*)(lA + r0 * DDIM), 16, 0, 0);
    }
    __syncthreads();                     // A staged; scratch zeroed

    #pragma unroll 1                     // sequential halves: acc stays 32 regs
    for (int h = 0; h < 2; ++h) {
        const unsigned char* gB =
            Bp + (size_t)(ct + h * 64 + wc * 32 + l31) * DDIM + kh * 32;

        f32x16 acc0, acc1;
        #pragma unroll
        for (int r = 0; r < 16; ++r) { acc0[r] = 0.f; acc1[r] = 0.f; }

        #pragma unroll
        for (int kt = 0; kt < 2; ++kt) {
            #pragma unroll
            for (int ks = 0; ks < 2; ++ks) {     // 4 x K=64, no barriers
                const int g0   = kt * 8 + ks * 4 + kh * 2;  // even granule
                const int off0 = (g0 ^ key) * 16;
                const int off1 = off0 ^ 16;
                const int bo   = kt * 128 + ks * 64;
                i32x8 a0, a1, bv;
                *((i32x4*)&a0)     = *(const i32x4*)(lA + aoff0 + off0);
                *((i32x4*)&a0 + 1) = *(const i32x4*)(lA + aoff0 + off1);
                *((i32x4*)&a1)     = *(const i32x4*)(lA + aoff1 + off0);
                *((i32x4*)&a1 + 1) = *(const i32x4*)(lA + aoff1 + off1);
                *((i32x4*)&bv)     = *(const i32x4*)(gB + bo);
                *((i32x4*)&bv + 1) = *(const i32x4*)(gB + bo + 16);
                acc0 = __builtin_amdgcn_mfma_scale_f32_32x32x64_f8f6f4(
                    a0, bv, acc0, 0, 0, 0, 0x7F7F7F7F, 0, 0x7F7F7F7F);
                acc1 = __builtin_amdgcn_mfma_scale_f32_32x32x64_f8f6f4(
                    a1, bv, acc1, 0, 0, 0, 0x7F7F7F7F, 0, 0x7F7F7F7F);
            }
        }

        // C/D layout (32x32): col = lane&31, row = (reg&3)+8*(reg>>2)+4*kh.
        // acc = 2*log2e*s -> raw v_exp_f32. Owner-lane "+=" into scratch
        // (same lane owns the slot across both h -> race-free, no barrier).
        float cp0 = 0.f, cp1 = 0.f;
        #pragma unroll
        for (int r = 0; r < 16; ++r) {
            float e0 = __builtin_amdgcn_exp2f(acc0[r]);
            float e1 = __builtin_amdgcn_exp2f(acc1[r]);
            cp0 += e0;
            cp1 += e1;
            float v0 = row16_sum(e0);
            float v1 = row16_sum(e1);
            if ((lane & 15) == 0) {      // lanes 0,16,32,48
                int rloc = wr * 64 + 4 * kh + (r & 3) + 8 * (r >> 2);
                int sub16 = l31 >> 4;    // 0 for lanes 0/32, 1 for 16/48
                lds_rp[wc][sub16][rloc]      += v0;
                lds_rp[wc][sub16][rloc + 32] += v1;
            }
        }
        lds_cp[wr][kh][h * 64 + wc * 32 + l31] += cp0 + cp1;
    }
    __syncthreads();

    // Final combine: one atomic per row and per col of the 128x128 tile.
    if (tid < BM) {
        float s = lds_rp[0][0][tid] + lds_rp[0][1][tid]
                + lds_rp[1][0][tid] + lds_rp[1][1][tid];
        atomicAdd(&rowsum[rt + tid], s);
    } else if (colsum) {
        int c = tid - BM;                // 0..127
        float s = lds_cp[0][0][c] + lds_cp[0][1][c]
                + lds_cp[1][0][c] + lds_cp[1][1][c];
        atomicAdd(&colsum[ct + c], s);
    }
}

// 32 blocks x 256 threads, one row each; block-reduce then one atomicAdd.
__global__ __launch_bounds__(256) void finalize_kernel(
        const float* __restrict__ rs1, const float* __restrict__ rs2,
        const float* __restrict__ rbr, const float* __restrict__ rbc,
        const float* __restrict__ diag, float* __restrict__ out) {
    __shared__ float s4[4];
    const float E2 = 7.38905609893065f;   // exp(1/tau), tau=0.5
    int i = blockIdx.x * 256 + threadIdx.x;
    float den1 = rs1[i] + rbr[i] - E2;
    float den2 = rs2[i] + rbc[i] - E2;
    float v = 0.5f * (logf(den1) + logf(den2)) - diag[i];
    #pragma unroll
    for (int m = 1; m < 64; m <<= 1) v += __shfl_xor(v, m);
    if ((threadIdx.x & 63) == 0) s4[threadIdx.x >> 6] = v;
    __syncthreads();
    if (threadIdx.x == 0) {
        float t = (s4[0] + s4[1] + s4[2] + s4[3]) * (1.0f / (float)NROW);
        atomicAdd(out, t);
    }
}

extern "C" void kernel_launch(void* const* d_in, const int* in_sizes, int n_in,
                              void* d_out, int out_size, void* d_ws, size_t ws_size,
                              hipStream_t stream) {
    const float* h1 = (const float*)d_in[0];
    const float* h2 = (const float*)d_in[1];
    float* out = (float*)d_out;

    char* ws = (char*)d_ws;
    unsigned char* z1b = (unsigned char*)ws;                             // 2 MB
    unsigned char* z2b = (unsigned char*)(ws + (size_t)NROW * DDIM);     // 2 MB
    float* sums = (float*)(ws + (size_t)2 * NROW * DDIM);
    float* rs1  = sums;
    float* rs2  = sums + NROW;
    float* rbr  = sums + 2 * NROW;
    float* rbc  = sums + 3 * NROW;
    float* diag = sums + 4 * NROW;

    normalize_kernel<<<NROW / 4, 256, 0, stream>>>(h1, h2, z1b, z2b, diag,
                                                   rs1, rs2, rbr, rbc, out);

    expsum_kernel<<<NT_TOTAL, 256, 0, stream>>>(z1b, z2b, rs1, rs2, rbr, rbc);

    finalize_kernel<<<NROW / 256, 256, 0, stream>>>(rs1, rs2, rbr, rbc, diag, out);
}

// Round 14
// 139.843 us; speedup vs baseline: 1.9687x; 1.0431x over previous
//
#include <hip/hip_runtime.h>
#include <math.h>

#define NROW 8192
#define DDIM 256
#define BM 128
#define BN 128          // full tile per block; both 64-col halves interleaved
#define NT_SYM 2080     // 64*65/2 lower-triangular 128x128 tiles
#define NT_FULL 4096
#define NT_TOTAL (2 * NT_SYM + NT_FULL)   // 8256 tiles = grid

typedef __attribute__((ext_vector_type(16))) float f32x16;
typedef __attribute__((ext_vector_type(4)))  int   i32x4;
typedef __attribute__((ext_vector_type(8)))  int   i32x8;
typedef __attribute__((address_space(3))) unsigned int lds_u32;
typedef const __attribute__((address_space(1))) unsigned int glb_u32;

// DPP row_ror butterfly add: after ror 1,2,4,8 every lane of each 16-lane row
// holds the row sum. VALU pipe only — no DS traffic.
template <int CTRL>
static __device__ inline float dpp_ror_add(float v) {
    int s = __float_as_int(v);
    int r = __builtin_amdgcn_update_dpp(0, s, CTRL, 0xF, 0xF, true);
    return v + __int_as_float(r);
}
static __device__ inline float row16_sum(float v) {
    v = dpp_ror_add<0x121>(v);
    v = dpp_ror_add<0x122>(v);
    v = dpp_ror_add<0x124>(v);
    v = dpp_ror_add<0x128>(v);
    return v;
}

// Pack 4 floats -> 4 fp8 e4m3 bytes (HW cvt, OCP on gfx950 — self-consistent
// with the fp8 MFMA's decode).
static __device__ inline unsigned int pack_fp8x4(float a, float b, float c, float d) {
    int p = __builtin_amdgcn_cvt_pk_fp8_f32(a, b, 0, false);
    p = __builtin_amdgcn_cvt_pk_fp8_f32(c, d, p, true);
    return (unsigned int)p;
}

// One wave per row: L2-normalize H1/H2 rows, scale by sqrt(2*log2(e)) so the
// fp8 Gram entries come out as 2*log2(e)*s -> exp(2s) == exp2(acc).
// diag[row] = 2*dot(z1n,z2n) fp32 (exact). Zero-inits rowsums and out.
__global__ __launch_bounds__(256) void normalize_kernel(
        const float* __restrict__ h1, const float* __restrict__ h2,
        unsigned char* __restrict__ z1b, unsigned char* __restrict__ z2b,
        float* __restrict__ diag,
        float* __restrict__ rs1, float* __restrict__ rs2,
        float* __restrict__ rbr, float* __restrict__ rbc,
        float* __restrict__ out) {
    int wave = threadIdx.x >> 6;
    int lane = threadIdx.x & 63;
    int row  = blockIdx.x * 4 + wave;
    if (blockIdx.x == 0 && threadIdx.x == 0) out[0] = 0.f;
    const float4* p1 = (const float4*)(h1 + (size_t)row * DDIM);
    const float4* p2 = (const float4*)(h2 + (size_t)row * DDIM);
    float4 a = p1[lane];
    float4 b = p2[lane];
    float s1 = a.x*a.x + a.y*a.y + a.z*a.z + a.w*a.w;
    float s2 = b.x*b.x + b.y*b.y + b.z*b.z + b.w*b.w;
    #pragma unroll
    for (int m = 1; m < 64; m <<= 1) { s1 += __shfl_xor(s1, m); s2 += __shfl_xor(s2, m); }
    float r1 = 1.0f / fmaxf(sqrtf(s1), 1e-12f);
    float r2 = 1.0f / fmaxf(sqrtf(s2), 1e-12f);
    float n1x = a.x*r1, n1y = a.y*r1, n1z = a.z*r1, n1w = a.w*r1;
    float n2x = b.x*r2, n2y = b.y*r2, n2z = b.z*r2, n2w = b.w*r2;
    float dt = n1x*n2x + n1y*n2y + n1z*n2z + n1w*n2w;
    #pragma unroll
    for (int m = 1; m < 64; m <<= 1) dt += __shfl_xor(dt, m);
    if (lane == 0) {
        diag[row] = 2.0f * dt;
        rs1[row] = 0.f; rs2[row] = 0.f; rbr[row] = 0.f; rbc[row] = 0.f;
    }
    const float SC = 1.69864364f;   // sqrt(2 * log2(e))
    ((unsigned int*)(z1b + (size_t)row * DDIM))[lane] =
        pack_fp8x4(n1x*SC, n1y*SC, n1z*SC, n1w*SC);
    ((unsigned int*)(z2b + (size_t)row * DDIM))[lane] =
        pack_fp8x4(n2x*SC, n2y*SC, n2z*SC, n2w*SC);
}

// R16 = R15 with the two column halves MERGED (unroll-1 removed): acc[h][mi]
// = 4 x f32x16 (64 regs, fits (256,4)'s 128-VGPR cap; ~115 est).
// Wins vs R15, targeting the conserved ~42us VALU busy (the invariant across
// the four 89-91us structures):
//  (a) DPP linearity: row r spans both halves -> row16_sum(e_h0 + e_h1)
//      does ONE reduction where R15 did two (DPP work halves);
//  (b) A fragments shared by both halves -> ds_reads halve (32 -> 16/wave);
//  (c) scratch becomes single plain writes (no zero-init, no LDS RMW);
//  (d) 4 independent MFMAs + 4 B-loads per ks, no barriers -> deeper ILP.
__global__ __launch_bounds__(256, 4) void expsum_kernel(
        const unsigned char* __restrict__ z1, const unsigned char* __restrict__ z2,
        float* __restrict__ rs1, float* __restrict__ rs2,
        float* __restrict__ rbr, float* __restrict__ rbc) {
    int t = blockIdx.x;
    int kind, tt;
    if (t < NT_SYM)            { kind = 0; tt = t; }
    else if (t < 2 * NT_SYM)   { kind = 1; tt = t - NT_SYM; }
    else                       { kind = 2; tt = t - 2 * NT_SYM; }

    int by, bx;
    const unsigned char *Ap, *Bp;
    float *rowsum, *colsum;
    if (kind == 2) {
        by = tt >> 6; bx = tt & 63;
        Ap = z1; Bp = z2; rowsum = rbr; colsum = rbc;
    } else {
        by = (int)((sqrtf(8.0f * (float)tt + 1.0f) - 1.0f) * 0.5f);
        while ((by + 1) * (by + 2) / 2 <= tt) ++by;
        while (by * (by + 1) / 2 > tt) --by;
        bx = tt - by * (by + 1) / 2;          // bx <= by
        const unsigned char* z = (kind == 0) ? z1 : z2;
        Ap = z; Bp = z;
        rowsum = (kind == 0) ? rs1 : rs2;
        colsum = (bx == by) ? nullptr : rowsum;
    }

    const int rt = by * BM;
    const int ct = bx * BN;

    __shared__ __align__(16) unsigned char lA[BM * DDIM];  // 32 KB full-K A
    __shared__ float lds_rp[2][2][BM];                     // [wc][sub16][row] 2 KB
    __shared__ float lds_cp[2][2][BN];                     // [wr][kh][col]    2 KB

    const int tid  = threadIdx.x;
    const int lane = tid & 63;
    const int wid  = tid >> 6;
    const int wr   = wid & 1;            // 64-row half
    const int wc   = wid >> 1;           // 32-col quarter (of a 64-col half)
    const int l31  = lane & 31;
    const int kh   = lane >> 5;          // k-half of the 64-wide k-step

    // DMA lane mapping: 16 lanes per 256-B row, 4 rows per wave-instruction.
    const int srow = lane >> 4;          // row within 4-row group
    const int sgt  = lane & 15;          // physical 16B granule (= DMA slot)

    const int key  = lane & 15;          // read-side swizzle key (= row&15)

    const int aoff0 = (wr * 64 + l31) * DDIM;        // rows 0..31 of wave tile
    const int aoff1 = aoff0 + 32 * DDIM;             // rows 32..63

    // Stage full 128x256B A: 32 wave-DMAs, 8 per wave, 16 B/lane, linear
    // dest, swizzled source granule gg = sgt ^ (r&15).
    #pragma unroll
    for (int p = 0; p < 8; ++p) {
        int r0 = (p * 4 + wid) * 4;
        int r  = r0 + srow;
        int gg = sgt ^ (r & 15);
        const unsigned char* ga = Ap + (size_t)(rt + r) * DDIM + gg * 16;
        __builtin_amdgcn_global_load_lds((glb_u32*)ga, (lds_u32*)(lA + r0 * DDIM), 16, 0, 0);
    }
    __syncthreads();                     // A staged

    // B bases for the two column halves.
    const unsigned char* gB0 = Bp + (size_t)(ct + wc * 32 + l31) * DDIM + kh * 32;
    const unsigned char* gB1 = gB0 + (size_t)64 * DDIM;

    f32x16 c00, c01, c10, c11;           // acc[h][mi]
    #pragma unroll
    for (int r = 0; r < 16; ++r) { c00[r] = 0.f; c01[r] = 0.f; c10[r] = 0.f; c11[r] = 0.f; }

    #pragma unroll
    for (int kt = 0; kt < 2; ++kt) {
        #pragma unroll
        for (int ks = 0; ks < 2; ++ks) {     // 4 x K=64, no barriers
            const int g0   = kt * 8 + ks * 4 + kh * 2;  // even granule
            const int off0 = (g0 ^ key) * 16;
            const int off1 = off0 ^ 16;
            const int bo   = kt * 128 + ks * 64;
            i32x8 a0, a1, b0, b1;
            *((i32x4*)&a0)     = *(const i32x4*)(lA + aoff0 + off0);
            *((i32x4*)&a0 + 1) = *(const i32x4*)(lA + aoff0 + off1);
            *((i32x4*)&a1)     = *(const i32x4*)(lA + aoff1 + off0);
            *((i32x4*)&a1 + 1) = *(const i32x4*)(lA + aoff1 + off1);
            *((i32x4*)&b0)     = *(const i32x4*)(gB0 + bo);
            *((i32x4*)&b0 + 1) = *(const i32x4*)(gB0 + bo + 16);
            *((i32x4*)&b1)     = *(const i32x4*)(gB1 + bo);
            *((i32x4*)&b1 + 1) = *(const i32x4*)(gB1 + bo + 16);
            c00 = __builtin_amdgcn_mfma_scale_f32_32x32x64_f8f6f4(
                a0, b0, c00, 0, 0, 0, 0x7F7F7F7F, 0, 0x7F7F7F7F);
            c01 = __builtin_amdgcn_mfma_scale_f32_32x32x64_f8f6f4(
                a1, b0, c01, 0, 0, 0, 0x7F7F7F7F, 0, 0x7F7F7F7F);
            c10 = __builtin_amdgcn_mfma_scale_f32_32x32x64_f8f6f4(
                a0, b1, c10, 0, 0, 0, 0x7F7F7F7F, 0, 0x7F7F7F7F);
            c11 = __builtin_amdgcn_mfma_scale_f32_32x32x64_f8f6f4(
                a1, b1, c11, 0, 0, 0, 0x7F7F7F7F, 0, 0x7F7F7F7F);
        }
    }

    // C/D layout (32x32): col = lane&31, row = (reg&3)+8*(reg>>2)+4*kh.
    // acc = 2*log2e*s -> raw v_exp_f32 (inputs bounded ~|2.9|).
    // Row sums span both halves -> reduce e_h0+e_h1 ONCE (DPP is linear).
    // Writer lanes 0/16/32/48 store plain (each slot exactly once).
    float cp0 = 0.f, cp1 = 0.f;
    #pragma unroll
    for (int r = 0; r < 16; ++r) {
        float e00 = __builtin_amdgcn_exp2f(c00[r]);   // h=0, rows mi=0
        float e01 = __builtin_amdgcn_exp2f(c01[r]);   // h=0, rows mi=1
        float e10 = __builtin_amdgcn_exp2f(c10[r]);   // h=1, rows mi=0
        float e11 = __builtin_amdgcn_exp2f(c11[r]);   // h=1, rows mi=1
        cp0 += e00 + e01;                 // same column, both row blocks
        cp1 += e10 + e11;
        float v0 = row16_sum(e00 + e10);  // row block mi=0, cols of both halves
        float v1 = row16_sum(e01 + e11);  // row block mi=1
        if ((lane & 15) == 0) {           // lanes 0,16,32,48
            int rloc = wr * 64 + 4 * kh + (r & 3) + 8 * (r >> 2);
            int sub16 = l31 >> 4;         // 0 for lanes 0/32, 1 for 16/48
            lds_rp[wc][sub16][rloc]      = v0;
            lds_rp[wc][sub16][rloc + 32] = v1;
        }
    }
    lds_cp[wr][kh][wc * 32 + l31]      = cp0;   // h=0 columns
    lds_cp[wr][kh][64 + wc * 32 + l31] = cp1;   // h=1 columns
    __syncthreads();

    // Final combine: one atomic per row and per col of the 128x128 tile.
    if (tid < BM) {
        float s = lds_rp[0][0][tid] + lds_rp[0][1][tid]
                + lds_rp[1][0][tid] + lds_rp[1][1][tid];
        atomicAdd(&rowsum[rt + tid], s);
    } else if (colsum) {
        int c = tid - BM;                // 0..127
        float s = lds_cp[0][0][c] + lds_cp[0][1][c]
                + lds_cp[1][0][c] + lds_cp[1][1][c];
        atomicAdd(&colsum[ct + c], s);
    }
}

// 32 blocks x 256 threads, one row each; block-reduce then one atomicAdd.
__global__ __launch_bounds__(256) void finalize_kernel(
        const float* __restrict__ rs1, const float* __restrict__ rs2,
        const float* __restrict__ rbr, const float* __restrict__ rbc,
        const float* __restrict__ diag, float* __restrict__ out) {
    __shared__ float s4[4];
    const float E2 = 7.38905609893065f;   // exp(1/tau), tau=0.5
    int i = blockIdx.x * 256 + threadIdx.x;
    float den1 = rs1[i] + rbr[i] - E2;
    float den2 = rs2[i] + rbc[i] - E2;
    float v = 0.5f * (logf(den1) + logf(den2)) - diag[i];
    #pragma unroll
    for (int m = 1; m < 64; m <<= 1) v += __shfl_xor(v, m);
    if ((threadIdx.x & 63) == 0) s4[threadIdx.x >> 6] = v;
    __syncthreads();
    if (threadIdx.x == 0) {
        float t = (s4[0] + s4[1] + s4[2] + s4[3]) * (1.0f / (float)NROW);
        atomicAdd(out, t);
    }
}

extern "C" void kernel_launch(void* const* d_in, const int* in_sizes, int n_in,
                              void* d_out, int out_size, void* d_ws, size_t ws_size,
                              hipStream_t stream) {
    const float* h1 = (const float*)d_in[0];
    const float* h2 = (const float*)d_in[1];
    float* out = (float*)d_out;

    char* ws = (char*)d_ws;
    unsigned char* z1b = (unsigned char*)ws;                             // 2 MB
    unsigned char* z2b = (unsigned char*)(ws + (size_t)NROW * DDIM);     // 2 MB
    float* sums = (float*)(ws + (size_t)2 * NROW * DDIM);
    float* rs1  = sums;
    float* rs2  = sums + NROW;
    float* rbr  = sums + 2 * NROW;
    float* rbc  = sums + 3 * NROW;
    float* diag = sums + 4 * NROW;

    normalize_kernel<<<NROW / 4, 256, 0, stream>>>(h1, h2, z1b, z2b, diag,
                                                   rs1, rs2, rbr, rbc, out);

    expsum_kernel<<<NT_TOTAL, 256, 0, stream>>>(z1b, z2b, rs1, rs2, rbr, rbc);

    finalize_kernel<<<NROW / 256, 256, 0, stream>>>(rs1, rs2, rbr, rbc, diag, out);
}

// Round 15
// 137.928 us; speedup vs baseline: 1.9960x; 1.0139x over previous
//
#include <hip/hip_runtime.h>
#include <math.h>

#define NROW 8192
#define DDIM 256
#define BM 128
#define BN 128          // full tile per block; 8 waves of 64x32 sub-tiles
#define NT_SYM 2080     // 64*65/2 lower-triangular 128x128 tiles
#define NT_FULL 4096
#define NT_TOTAL (2 * NT_SYM + NT_FULL)   // 8256 tiles = grid

typedef __attribute__((ext_vector_type(16))) float f32x16;
typedef __attribute__((ext_vector_type(4)))  int   i32x4;
typedef __attribute__((ext_vector_type(8)))  int   i32x8;
typedef __attribute__((address_space(3))) unsigned int lds_u32;
typedef const __attribute__((address_space(1))) unsigned int glb_u32;

// DPP row_ror butterfly add: after ror 1,2,4,8 every lane of each 16-lane row
// holds the row sum. VALU pipe only — no DS traffic.
template <int CTRL>
static __device__ inline float dpp_ror_add(float v) {
    int s = __float_as_int(v);
    int r = __builtin_amdgcn_update_dpp(0, s, CTRL, 0xF, 0xF, true);
    return v + __int_as_float(r);
}
static __device__ inline float row16_sum(float v) {
    v = dpp_ror_add<0x121>(v);
    v = dpp_ror_add<0x122>(v);
    v = dpp_ror_add<0x124>(v);
    v = dpp_ror_add<0x128>(v);
    return v;
}

// Pack 4 floats -> 4 fp8 e4m3 bytes (HW cvt, OCP on gfx950 — self-consistent
// with the fp8 MFMA's decode).
static __device__ inline unsigned int pack_fp8x4(float a, float b, float c, float d) {
    int p = __builtin_amdgcn_cvt_pk_fp8_f32(a, b, 0, false);
    p = __builtin_amdgcn_cvt_pk_fp8_f32(c, d, p, true);
    return (unsigned int)p;
}

// One wave per row: L2-normalize H1/H2 rows, scale by sqrt(2*log2(e)) so the
// fp8 Gram entries come out as 2*log2(e)*s -> exp(2s) == exp2(acc).
// diag[row] = 2*dot(z1n,z2n) fp32 (exact). Zero-inits rowsums and out.
__global__ __launch_bounds__(256) void normalize_kernel(
        const float* __restrict__ h1, const float* __restrict__ h2,
        unsigned char* __restrict__ z1b, unsigned char* __restrict__ z2b,
        float* __restrict__ diag,
        float* __restrict__ rs1, float* __restrict__ rs2,
        float* __restrict__ rbr, float* __restrict__ rbc,
        float* __restrict__ out) {
    int wave = threadIdx.x >> 6;
    int lane = threadIdx.x & 63;
    int row  = blockIdx.x * 4 + wave;
    if (blockIdx.x == 0 && threadIdx.x == 0) out[0] = 0.f;
    const float4* p1 = (const float4*)(h1 + (size_t)row * DDIM);
    const float4* p2 = (const float4*)(h2 + (size_t)row * DDIM);
    float4 a = p1[lane];
    float4 b = p2[lane];
    float s1 = a.x*a.x + a.y*a.y + a.z*a.z + a.w*a.w;
    float s2 = b.x*b.x + b.y*b.y + b.z*b.z + b.w*b.w;
    #pragma unroll
    for (int m = 1; m < 64; m <<= 1) { s1 += __shfl_xor(s1, m); s2 += __shfl_xor(s2, m); }
    float r1 = 1.0f / fmaxf(sqrtf(s1), 1e-12f);
    float r2 = 1.0f / fmaxf(sqrtf(s2), 1e-12f);
    float n1x = a.x*r1, n1y = a.y*r1, n1z = a.z*r1, n1w = a.w*r1;
    float n2x = b.x*r2, n2y = b.y*r2, n2z = b.z*r2, n2w = b.w*r2;
    float dt = n1x*n2x + n1y*n2y + n1z*n2z + n1w*n2w;
    #pragma unroll
    for (int m = 1; m < 64; m <<= 1) dt += __shfl_xor(dt, m);
    if (lane == 0) {
        diag[row] = 2.0f * dt;
        rs1[row] = 0.f; rs2[row] = 0.f; rbr[row] = 0.f; rbc[row] = 0.f;
    }
    const float SC = 1.69864364f;   // sqrt(2 * log2(e))
    ((unsigned int*)(z1b + (size_t)row * DDIM))[lane] =
        pack_fp8x4(n1x*SC, n1y*SC, n1z*SC, n1w*SC);
    ((unsigned int*)(z2b + (size_t)row * DDIM))[lane] =
        pack_fp8x4(n2x*SC, n2y*SC, n2z*SC, n2w*SC);
}

// R17 = R16's tile/math with 512-thread blocks: 8 waves of 64x32 sub-tiles
// -> acc = 32 regs/wave (total ~72 <= 85 cap of launch_bounds(512,6)) ->
// 6 waves/SIMD, 24 waves/CU (+50% vs R16's VGPR-gated 16). Rationale: R16
// showed per-tile work near floor with all pipes <40% busy — concurrency is
// the remaining lever, and it was gated by the 64-reg accumulator. Costs
// (accepted: both pipes have headroom): A ds_reads shared 4-way not 2-way
// (DS 18%->~30%), DPP per col-half (VALU 38%->~50%).
// Scratch [4][2][128]+[2][2][128] = 6 KB, every slot written exactly once.
__global__ __launch_bounds__(512, 6) void expsum_kernel(
        const unsigned char* __restrict__ z1, const unsigned char* __restrict__ z2,
        float* __restrict__ rs1, float* __restrict__ rs2,
        float* __restrict__ rbr, float* __restrict__ rbc) {
    int t = blockIdx.x;
    int kind, tt;
    if (t < NT_SYM)            { kind = 0; tt = t; }
    else if (t < 2 * NT_SYM)   { kind = 1; tt = t - NT_SYM; }
    else                       { kind = 2; tt = t - 2 * NT_SYM; }

    int by, bx;
    const unsigned char *Ap, *Bp;
    float *rowsum, *colsum;
    if (kind == 2) {
        by = tt >> 6; bx = tt & 63;
        Ap = z1; Bp = z2; rowsum = rbr; colsum = rbc;
    } else {
        by = (int)((sqrtf(8.0f * (float)tt + 1.0f) - 1.0f) * 0.5f);
        while ((by + 1) * (by + 2) / 2 <= tt) ++by;
        while (by * (by + 1) / 2 > tt) --by;
        bx = tt - by * (by + 1) / 2;          // bx <= by
        const unsigned char* z = (kind == 0) ? z1 : z2;
        Ap = z; Bp = z;
        rowsum = (kind == 0) ? rs1 : rs2;
        colsum = (bx == by) ? nullptr : rowsum;
    }

    const int rt = by * BM;
    const int ct = bx * BN;

    __shared__ __align__(16) unsigned char lA[BM * DDIM];  // 32 KB full-K A
    __shared__ float lds_rp[4][2][BM];                     // [wc4][sub16][row] 4 KB
    __shared__ float lds_cp[2][2][BN];                     // [wr][kh][col]     2 KB

    const int tid  = threadIdx.x;
    const int lane = tid & 63;
    const int wid  = tid >> 6;           // 0..7
    const int wr   = wid & 1;            // 64-row half
    const int wc4  = wid >> 1;           // 32-col quarter (0..3)
    const int l31  = lane & 31;
    const int kh   = lane >> 5;          // k-half of the 64-wide k-step

    // DMA lane mapping: 16 lanes per 256-B row, 4 rows per wave-instruction.
    const int srow = lane >> 4;          // row within 4-row group
    const int sgt  = lane & 15;          // physical 16B granule (= DMA slot)

    const int key  = lane & 15;          // read-side swizzle key (= row&15)

    const int aoff0 = (wr * 64 + l31) * DDIM;        // rows 0..31 of wave tile
    const int aoff1 = aoff0 + 32 * DDIM;             // rows 32..63

    // Stage full 128x256B A: 32 wave-DMAs, 4 per wave, 16 B/lane, linear
    // dest, swizzled source granule gg = sgt ^ (r&15).
    #pragma unroll
    for (int p = 0; p < 4; ++p) {
        int r0 = (p * 8 + wid) * 4;
        int r  = r0 + srow;
        int gg = sgt ^ (r & 15);
        const unsigned char* ga = Ap + (size_t)(rt + r) * DDIM + gg * 16;
        __builtin_amdgcn_global_load_lds((glb_u32*)ga, (lds_u32*)(lA + r0 * DDIM), 16, 0, 0);
    }
    __syncthreads();                     // A staged

    // B base: this wave's 32 cols, per-lane row ct + wc4*32 + l31.
    const unsigned char* gB = Bp + (size_t)(ct + wc4 * 32 + l31) * DDIM + kh * 32;

    f32x16 acc0, acc1;                   // rows mi=0 / mi=1 of the 64-row half
    #pragma unroll
    for (int r = 0; r < 16; ++r) { acc0[r] = 0.f; acc1[r] = 0.f; }

    #pragma unroll
    for (int kt = 0; kt < 2; ++kt) {
        #pragma unroll
        for (int ks = 0; ks < 2; ++ks) {     // 4 x K=64, no barriers
            const int g0   = kt * 8 + ks * 4 + kh * 2;  // even granule
            const int off0 = (g0 ^ key) * 16;
            const int off1 = off0 ^ 16;
            const int bo   = kt * 128 + ks * 64;
            i32x8 a0, a1, bv;
            *((i32x4*)&a0)     = *(const i32x4*)(lA + aoff0 + off0);
            *((i32x4*)&a0 + 1) = *(const i32x4*)(lA + aoff0 + off1);
            *((i32x4*)&a1)     = *(const i32x4*)(lA + aoff1 + off0);
            *((i32x4*)&a1 + 1) = *(const i32x4*)(lA + aoff1 + off1);
            *((i32x4*)&bv)     = *(const i32x4*)(gB + bo);
            *((i32x4*)&bv + 1) = *(const i32x4*)(gB + bo + 16);
            acc0 = __builtin_amdgcn_mfma_scale_f32_32x32x64_f8f6f4(
                a0, bv, acc0, 0, 0, 0, 0x7F7F7F7F, 0, 0x7F7F7F7F);
            acc1 = __builtin_amdgcn_mfma_scale_f32_32x32x64_f8f6f4(
                a1, bv, acc1, 0, 0, 0, 0x7F7F7F7F, 0, 0x7F7F7F7F);
        }
    }

    // C/D layout (32x32): col = lane&31, row = (reg&3)+8*(reg>>2)+4*kh.
    // acc = 2*log2e*s -> raw v_exp_f32 (inputs bounded ~|2.9|).
    // Writers (lanes 0/16/32/48) store plain — every scratch slot exactly
    // once across the 8 waves (1024 slots = 8 waves x 128 writes).
    float cp = 0.f;
    #pragma unroll
    for (int r = 0; r < 16; ++r) {
        float e0 = __builtin_amdgcn_exp2f(acc0[r]);
        float e1 = __builtin_amdgcn_exp2f(acc1[r]);
        cp += e0 + e1;                    // same col, rows of both mi blocks
        float v0 = row16_sum(e0);
        float v1 = row16_sum(e1);
        if ((lane & 15) == 0) {           // lanes 0,16,32,48
            int rloc = wr * 64 + 4 * kh + (r & 3) + 8 * (r >> 2);
            int sub16 = l31 >> 4;         // 16-col group within the 32 cols
            lds_rp[wc4][sub16][rloc]      = v0;
            lds_rp[wc4][sub16][rloc + 32] = v1;
        }
    }
    lds_cp[wr][kh][wc4 * 32 + l31] = cp;
    __syncthreads();

    // Final combine: one atomic per row and per col of the 128x128 tile.
    if (tid < BM) {
        float s = lds_rp[0][0][tid] + lds_rp[0][1][tid]
                + lds_rp[1][0][tid] + lds_rp[1][1][tid]
                + lds_rp[2][0][tid] + lds_rp[2][1][tid]
                + lds_rp[3][0][tid] + lds_rp[3][1][tid];
        atomicAdd(&rowsum[rt + tid], s);
    } else if (colsum && tid < 2 * BM) {
        int c = tid - BM;                // 0..127
        float s = lds_cp[0][0][c] + lds_cp[0][1][c]
                + lds_cp[1][0][c] + lds_cp[1][1][c];
        atomicAdd(&colsum[ct + c], s);
    }
}

// 32 blocks x 256 threads, one row each; block-reduce then one atomicAdd.
__global__ __launch_bounds__(256) void finalize_kernel(
        const float* __restrict__ rs1, const float* __restrict__ rs2,
        const float* __restrict__ rbr, const float* __restrict__ rbc,
        const float* __restrict__ diag, float* __restrict__ out) {
    __shared__ float s4[4];
    const float E2 = 7.38905609893065f;   // exp(1/tau), tau=0.5
    int i = blockIdx.x * 256 + threadIdx.x;
    float den1 = rs1[i] + rbr[i] - E2;
    float den2 = rs2[i] + rbc[i] - E2;
    float v = 0.5f * (logf(den1) + logf(den2)) - diag[i];
    #pragma unroll
    for (int m = 1; m < 64; m <<= 1) v += __shfl_xor(v, m);
    if ((threadIdx.x & 63) == 0) s4[threadIdx.x >> 6] = v;
    __syncthreads();
    if (threadIdx.x == 0) {
        float t = (s4[0] + s4[1] + s4[2] + s4[3]) * (1.0f / (float)NROW);
        atomicAdd(out, t);
    }
}

extern "C" void kernel_launch(void* const* d_in, const int* in_sizes, int n_in,
                              void* d_out, int out_size, void* d_ws, size_t ws_size,
                              hipStream_t stream) {
    const float* h1 = (const float*)d_in[0];
    const float* h2 = (const float*)d_in[1];
    float* out = (float*)d_out;

    char* ws = (char*)d_ws;
    unsigned char* z1b = (unsigned char*)ws;                             // 2 MB
    unsigned char* z2b = (unsigned char*)(ws + (size_t)NROW * DDIM);     // 2 MB
    float* sums = (float*)(ws + (size_t)2 * NROW * DDIM);
    float* rs1  = sums;
    float* rs2  = sums + NROW;
    float* rbr  = sums + 2 * NROW;
    float* rbc  = sums + 3 * NROW;
    float* diag = sums + 4 * NROW;

    normalize_kernel<<<NROW / 4, 256, 0, stream>>>(h1, h2, z1b, z2b, diag,
                                                   rs1, rs2, rbr, rbc, out);

    expsum_kernel<<<NT_TOTAL, 512, 0, stream>>>(z1b, z2b, rs1, rs2, rbr, rbc);

    finalize_kernel<<<NROW / 256, 256, 0, stream>>>(rs1, rs2, rbr, rbc, diag, out);
}